// Round 13
// baseline (116.977 us; speedup 1.0000x reference)
//
#include <hip/hip_runtime.h>
#include <hip/hip_bf16.h>
#include <math.h>

// Problem constants
#define L_SEQ 4096
#define CDIM  512
#define NH    8
#define NKV   2
#define HD    64
#define EPS   1e-6f
// 1/sqrt(64) * log2(e), folded into Q so attn P = exp2(S) directly
#define QSCALE 0.18033688011f
#define NSPLIT 4

using short8 = __attribute__((ext_vector_type(8))) short;
using f32x4  = __attribute__((ext_vector_type(4))) float;
using f32x16 = __attribute__((ext_vector_type(16))) float;
typedef unsigned short ushort_t;

// RNE float -> bf16 bits
__device__ __forceinline__ ushort_t f2bf(float f) {
    union { float f; unsigned u; } c; c.f = f;
    unsigned r = c.u + 0x7FFF + ((c.u >> 16) & 1);
    return (ushort_t)(r >> 16);
}
__device__ __forceinline__ float bf2f(ushort_t u) {
    union { unsigned u; float f; } c; c.u = ((unsigned)u) << 16;
    return c.f;
}

// async global->LDS, 16B per lane; LDS dest = wave-uniform base + lane*16
#define GLOAD_LDS16(g, l)                                                  \
    __builtin_amdgcn_global_load_lds(                                      \
        (const __attribute__((address_space(1))) unsigned int*)(g),        \
        (__attribute__((address_space(3))) unsigned int*)(l), 16, 0, 0)

__device__ __forceinline__ short8 lds_read8(const char* p) {
    return *reinterpret_cast<const short8*>(__builtin_assume_aligned(p, 16));
}

// pack two floats to one u32 of 2 bf16 (lo in low short)
__device__ __forceinline__ unsigned pk_bf16(float lo, float hi) {
    const __hip_bfloat162 h2 = __float22bfloat162_rn(make_float2(lo, hi));
    unsigned w; __builtin_memcpy(&w, &h2, 4);
    return w;
}

// ---------------------------------------------------------------------------
// f32 -> bf16 conversion for x and the 4 weights (one launch).
// ---------------------------------------------------------------------------
__global__ __launch_bounds__(256) void cvt_bf16(const float* __restrict__ x,
                                                const float* __restrict__ wq,
                                                const float* __restrict__ wk,
                                                const float* __restrict__ wv,
                                                const float* __restrict__ wo,
                                                ushort_t* __restrict__ xb,
                                                ushort_t* __restrict__ wqb,
                                                ushort_t* __restrict__ wkb,
                                                ushort_t* __restrict__ wvb,
                                                ushort_t* __restrict__ wob) {
    const size_t i = ((size_t)blockIdx.x * 256 + threadIdx.x) << 2;
    const float* s; ushort_t* d; size_t o;
    if (i < 2097152)      { s = x;  d = xb;  o = i; }
    else if (i < 2359296) { s = wq; d = wqb; o = i - 2097152; }
    else if (i < 2424832) { s = wk; d = wkb; o = i - 2359296; }
    else if (i < 2490368) { s = wv; d = wvb; o = i - 2424832; }
    else                  { s = wo; d = wob; o = i - 2490368; }
    const float4 v = *reinterpret_cast<const float4*>(s + o);
    ushort_t r[4] = { f2bf(v.x), f2bf(v.y), f2bf(v.z), f2bf(v.w) };
    *reinterpret_cast<uint2*>(d + o) = *reinterpret_cast<const uint2*>(r);
}

// ===========================================================================
// 128x128-tile bf16 GEMM core (m93/m97 structure): BK=64, 4 waves (2x2),
// each wave computes a 64x64 sub-tile as 4x4 fragments of 16x16x32 MFMA.
// Staging: 16 chunks (8 rows x 128B) per matrix via global_load_lds,
// inverse-swizzled source + swizzled b128 reads, double-buffered.
// Expanded inline in qkv_gemm128 (fused norm epilogue) and gemm128_wo.
// ===========================================================================
#define GEMM128_CORE(A_, B_, K_)                                              \
    const int tid = threadIdx.x;                                              \
    const int w = tid >> 6, lane = tid & 63;                                  \
    const int g = lane >> 4, r16 = lane & 15;                                 \
    const int wr = w >> 1, wc = w & 1;                                        \
    const int r7sw = (r16 & 7) << 4;                                          \
    const int lrow = lane >> 3;                                               \
    const int swzb = ((lane & 7) ^ lrow) << 4;                                \
    char* As[2] = { smem, smem + 16384 };                                     \
    char* Bs[2] = { smem + 32768, smem + 49152 };                             \
    const size_t rowK2 = (size_t)(K_) * 2;                                    \
    const char* ag[4]; const char* bg[4];                                     \
    _Pragma("unroll")                                                         \
    for (int c = 0; c < 4; ++c) {                                             \
        const int ch = w * 4 + c;                                             \
        ag[c] = (const char*)(A_) + (size_t)(m0 + ch * 8 + lrow) * rowK2 + swzb; \
        bg[c] = (const char*)(B_) + (size_t)(n0 + ch * 8 + lrow) * rowK2 + swzb; \
    }                                                                         \
    _Pragma("unroll")                                                         \
    for (int c = 0; c < 4; ++c) {                                             \
        GLOAD_LDS16(ag[c], As[0] + (w * 4 + c) * 1024);                       \
        GLOAD_LDS16(bg[c], Bs[0] + (w * 4 + c) * 1024);                       \
    }                                                                         \
    __syncthreads();                                                          \
    f32x4 acc[4][4] = {};                                                     \
    const int NKIT = (K_) >> 6;                                               \
    int cur = 0;                                                              \
    for (int it = 0; it < NKIT; ++it) {                                       \
        if (it + 1 < NKIT) {                                                  \
            const size_t ko = (size_t)(it + 1) * 128;                         \
            _Pragma("unroll")                                                 \
            for (int c = 0; c < 4; ++c) {                                     \
                GLOAD_LDS16(ag[c] + ko, As[cur ^ 1] + (w * 4 + c) * 1024);    \
                GLOAD_LDS16(bg[c] + ko, Bs[cur ^ 1] + (w * 4 + c) * 1024);    \
            }                                                                 \
        }                                                                     \
        const char* at = As[cur];                                             \
        const char* bt = Bs[cur];                                             \
        short8 af[4][2], bf[4][2];                                            \
        _Pragma("unroll")                                                     \
        for (int t = 0; t < 4; ++t)                                           \
            _Pragma("unroll")                                                 \
            for (int ks = 0; ks < 2; ++ks) {                                  \
                af[t][ks] = lds_read8(at + (wr * 64 + t * 16 + r16) * 128     \
                                         + ((ks * 64 + g * 16) ^ r7sw));      \
                bf[t][ks] = lds_read8(bt + (wc * 64 + t * 16 + r16) * 128     \
                                         + ((ks * 64 + g * 16) ^ r7sw));      \
            }                                                                 \
        __builtin_amdgcn_s_setprio(1);                                        \
        _Pragma("unroll")                                                     \
        for (int tm = 0; tm < 4; ++tm)                                        \
            _Pragma("unroll")                                                 \
            for (int tn = 0; tn < 4; ++tn)                                    \
                _Pragma("unroll")                                             \
                for (int ks = 0; ks < 2; ++ks)                                \
                    acc[tm][tn] = __builtin_amdgcn_mfma_f32_16x16x32_bf16(    \
                        af[tm][ks], bf[tn][ks], acc[tm][tn], 0, 0, 0);        \
        __builtin_amdgcn_s_setprio(0);                                        \
        __syncthreads();                                                      \
        cur ^= 1;                                                             \
    }

// ---------------------------------------------------------------------------
// Fused QKV projection, 128^2 tiles (one launch, 192 blocks):
//   bid <  128 : Q  = xb * Wq^T  [4096][512]  + fused RMSNorm+RoPE
//   bid <  160 : K  = xb * Wk^T  [4096][128]  + fused RMSNorm+RoPE
//   bid >= 160 : Vt = Wv * xb^T  [128][4096]  plain bf16 store
// ---------------------------------------------------------------------------
__global__ __launch_bounds__(256, 2) void qkv_gemm128(const ushort_t* __restrict__ xb,
                                                      const ushort_t* __restrict__ wqb,
                                                      const ushort_t* __restrict__ wkb,
                                                      const ushort_t* __restrict__ wvb,
                                                      const float* __restrict__ qnw,
                                                      const float* __restrict__ knw,
                                                      ushort_t* __restrict__ qbuf,
                                                      ushort_t* __restrict__ kbuf,
                                                      ushort_t* __restrict__ vtb) {
    __shared__ char smem[128 * 130 * 4];   // 66560 B: staging (64KB) U F[128][130]
    float (*F)[130] = (float(*)[130])smem;

    const int bid = blockIdx.x;
    int which, m0, n0;
    const ushort_t *A, *B;
    if (bid < 128)      { which = 0; A = xb;  B = wqb; m0 = (bid >> 2) * 128; n0 = (bid & 3) * 128; }
    else if (bid < 160) { which = 1; A = xb;  B = wkb; m0 = (bid - 128) * 128; n0 = 0; }
    else                { which = 2; A = wvb; B = xb;  m0 = 0; n0 = (bid - 160) * 128; }

    GEMM128_CORE(A, B, CDIM)

    if (which == 2) {
        // plain bf16 epilogue -> vtb [128][4096]
#pragma unroll
        for (int tm = 0; tm < 4; ++tm)
#pragma unroll
            for (int tn = 0; tn < 4; ++tn)
#pragma unroll
                for (int jj = 0; jj < 4; ++jj) {
                    const int row = m0 + wr * 64 + tm * 16 + g * 4 + jj;
                    const int col = n0 + wc * 64 + tn * 16 + r16;
                    vtb[(size_t)row * L_SEQ + col] = f2bf(acc[tm][tn][jj]);
                }
        return;
    }

    // ---- fused RMSNorm + RoPE epilogue (which = 0 Q, 1 K) ----
    // stage f32 tile into F (last loop __syncthreads freed the staging LDS)
#pragma unroll
    for (int tm = 0; tm < 4; ++tm)
#pragma unroll
        for (int tn = 0; tn < 4; ++tn)
#pragma unroll
            for (int jj = 0; jj < 4; ++jj)
                F[wr * 64 + tm * 16 + g * 4 + jj][wc * 64 + tn * 16 + r16] = acc[tm][tn][jj];
    __syncthreads();

    const float wq_ = qnw[lane], wk_ = knw[lane];
    const int i31 = lane & 31;
    const float invf = exp2f((float)i31 * -0.41524101186f);   // 10000^(-i/32)

    // 256 head-vectors in tile (128 rows x 2 head-halves); wave w handles
    // vecid = w + 4*v for v in [0,64).
    for (int v = 0; v < 64; ++v) {
        const int vecid = w + 4 * v;
        const int rl = vecid >> 1;         // row in tile
        const int hh = vecid & 1;          // head-half within 128 cols
        const int pos = m0 + rl;
        float x = F[rl][hh * 64 + lane];
        float ss = x * x;
#pragma unroll
        for (int off = 32; off; off >>= 1) ss += __shfl_xor(ss, off);
        const float wv_ = (which == 0) ? wq_ : wk_;
        float xn = x * rsqrtf(ss * (1.0f / 64.0f) + EPS) * wv_;
        float xp = __shfl_xor(xn, 32);
        float sn, cs;
        sincosf((float)pos * invf, &sn, &cs);
        float out = (lane < 32) ? (xn * cs - xp * sn) : (xn * cs + xp * sn);
        if (which == 0) {
            out *= QSCALE;
            qbuf[(size_t)pos * (NH * HD) + n0 + hh * 64 + lane] = f2bf(out);
        } else {
            kbuf[(size_t)pos * (NKV * HD) + hh * 64 + lane] = f2bf(out);
        }
    }
}

// ---------------------------------------------------------------------------
// Wo projection, 128^2 tiles: out[4096][512] f32 = abuf * Wo^T.
// ---------------------------------------------------------------------------
__global__ __launch_bounds__(256, 2) void gemm128_wo(const ushort_t* __restrict__ A_,
                                                     const ushort_t* __restrict__ B_,
                                                     float* __restrict__ C) {
    __shared__ char smem[65536];
    const int m0 = blockIdx.y * 128, n0 = blockIdx.x * 128;

    GEMM128_CORE(A_, B_, CDIM)

#pragma unroll
    for (int tm = 0; tm < 4; ++tm)
#pragma unroll
        for (int tn = 0; tn < 4; ++tn)
#pragma unroll
            for (int jj = 0; jj < 4; ++jj) {
                const int row = m0 + wr * 64 + tm * 16 + g * 4 + jj;
                const int col = n0 + wc * 64 + tn * 16 + r16;
                C[(size_t)row * CDIM + col] = acc[tm][tn][jj];
            }
}

// ---------------------------------------------------------------------------
// Flash attention (unchanged from round 12: QR=64, swapped QK^T 32x32,
// lane-local softmax, permlane32_swap, exp2f builtins). nsplit via gridDim.z.
// ---------------------------------------------------------------------------
__global__ __launch_bounds__(256, 2) void attn_mfma(const ushort_t* __restrict__ qb,
                                                    const ushort_t* __restrict__ kb,
                                                    const ushort_t* __restrict__ vtb,
                                                    ushort_t* __restrict__ opart,
                                                    float* __restrict__ lpart) {
    __shared__ short Ks[2][4096];
    __shared__ short Vs[2][4096];

    const int tid = threadIdx.x;
    const int w = tid >> 6, lane = tid & 63;
    const int l31 = lane & 31, hf = lane >> 5;
    const int h = blockIdx.y, hkv = h >> 2;
    const int s = blockIdx.z;
    const int kvspan = L_SEQ / gridDim.z;
    const int kvb = s * kvspan;
    const int qw = blockIdx.x * 256 + w * 64;
    const int swz = (lane & 7) << 4;

    const int lrow = lane >> 3;
    const int swzb = ((lane & 7) ^ lrow) << 4;
    const int c0 = w * 2, c1 = w * 2 + 1;

    const char* kgA = (const char*)kb + (size_t)(kvb + c0 * 8 + lrow) * (NKV * HD * 2)
                      + hkv * (HD * 2) + swzb;
    const char* kgB = kgA + 8 * (NKV * HD * 2);
    const char* vgA = (const char*)vtb + (size_t)(hkv * HD + c0 * 8 + lrow) * (L_SEQ * 2)
                      + (size_t)kvb * 2 + swzb;
    const char* vgB = vgA + 8 * (size_t)(L_SEQ * 2);

    short8 qf0[4], qf1[4];
#pragma unroll
    for (int ks = 0; ks < 4; ++ks) {
        qf0[ks] = *reinterpret_cast<const short8*>(
            &qb[(size_t)(qw + l31) * CDIM + h * HD + ks * 16 + hf * 8]);
        qf1[ks] = *reinterpret_cast<const short8*>(
            &qb[(size_t)(qw + 32 + l31) * CDIM + h * HD + ks * 16 + hf * 8]);
    }

    GLOAD_LDS16(kgA, (char*)Ks[0] + c0 * 1024);
    GLOAD_LDS16(kgB, (char*)Ks[0] + c1 * 1024);
    GLOAD_LDS16(vgA, (char*)Vs[0] + c0 * 1024);
    GLOAD_LDS16(vgB, (char*)Vs[0] + c1 * 1024);
    __syncthreads();

    f32x16 oacc0[2] = {}, oacc1[2] = {};
    float ls0[2] = {}, ls1[2] = {};

    int cur = 0;
    const int nit = kvspan >> 6;
    for (int it = 0; it < nit; ++it) {
        if (it + 1 < nit) {
            const size_t ko = (size_t)(it + 1) * 64 * (NKV * HD * 2);
            const size_t vo = (size_t)(it + 1) * 128;
            char* kd = (char*)Ks[cur ^ 1];
            char* vd = (char*)Vs[cur ^ 1];
            GLOAD_LDS16(kgA + ko, kd + c0 * 1024);
            GLOAD_LDS16(kgB + ko, kd + c1 * 1024);
            GLOAD_LDS16(vgA + vo, vd + c0 * 1024);
            GLOAD_LDS16(vgB + vo, vd + c1 * 1024);
        }

        const char* kt = (const char*)Ks[cur];
        const char* vt = (const char*)Vs[cur];

#pragma unroll
        for (int sub = 0; sub < 2; ++sub) {
            f32x16 s0 = {}, s1 = {};
            __builtin_amdgcn_s_setprio(1);
#pragma unroll
            for (int ks = 0; ks < 4; ++ks) {
                const short8 kfr = lds_read8(
                    kt + (sub * 32 + l31) * 128 + ((ks * 32 + hf * 16) ^ swz));
                s0 = __builtin_amdgcn_mfma_f32_32x32x16_bf16(kfr, qf0[ks], s0, 0, 0, 0);
                s1 = __builtin_amdgcn_mfma_f32_32x32x16_bf16(kfr, qf1[ks], s1, 0, 0, 0);
            }
            __builtin_amdgcn_s_setprio(0);

            unsigned pk0[8], pk1[8];
#pragma unroll
            for (int r2 = 0; r2 < 8; ++r2) {
                const float x0 = exp2f(s0[2 * r2]), y0 = exp2f(s0[2 * r2 + 1]);
                const float x1 = exp2f(s1[2 * r2]), y1 = exp2f(s1[2 * r2 + 1]);
                ls0[r2 & 1] += x0 + y0;
                ls1[r2 & 1] += x1 + y1;
                pk0[r2] = pk_bf16(x0, y0);
                pk1[r2] = pk_bf16(x1, y1);
            }

            short8 pf0[2], pf1[2];
#pragma unroll
            for (int kkl = 0; kkl < 2; ++kkl) {
                auto a0 = __builtin_amdgcn_permlane32_swap(pk0[kkl * 4 + 0], pk0[kkl * 4 + 2], false, false);
                auto a1 = __builtin_amdgcn_permlane32_swap(pk0[kkl * 4 + 1], pk0[kkl * 4 + 3], false, false);
                auto b0 = __builtin_amdgcn_permlane32_swap(pk1[kkl * 4 + 0], pk1[kkl * 4 + 2], false, false);
                auto b1 = __builtin_amdgcn_permlane32_swap(pk1[kkl * 4 + 1], pk1[kkl * 4 + 3], false, false);
                union { unsigned u[4]; short8 s8; } u0, u1;
                u0.u[0] = a0[0]; u0.u[1] = a1[0]; u0.u[2] = a0[1]; u0.u[3] = a1[1];
                u1.u[0] = b0[0]; u1.u[1] = b1[0]; u1.u[2] = b0[1]; u1.u[3] = b1[1];
                pf0[kkl] = u0.s8; pf1[kkl] = u1.s8;
            }

            __builtin_amdgcn_s_setprio(1);
#pragma unroll
            for (int n = 0; n < 2; ++n) {
#pragma unroll
                for (int kkl = 0; kkl < 2; ++kkl) {
                    const short8 vf = lds_read8(
                        vt + (n * 32 + l31) * 128 + (((sub * 2 + kkl) * 32 + hf * 16) ^ swz));
                    oacc0[n] = __builtin_amdgcn_mfma_f32_32x32x16_bf16(pf0[kkl], vf, oacc0[n], 0, 0, 0);
                    oacc1[n] = __builtin_amdgcn_mfma_f32_32x32x16_bf16(pf1[kkl], vf, oacc1[n], 0, 0, 0);
                }
            }
            __builtin_amdgcn_s_setprio(0);
        }

        __syncthreads();
        cur ^= 1;
    }

    float lsA = ls0[0] + ls0[1];
    float lsB = ls1[0] + ls1[1];
    lsA += __shfl_xor(lsA, 32);
    lsB += __shfl_xor(lsB, 32);
    ushort_t* op = opart + (size_t)s * L_SEQ * CDIM;
    float* lp = lpart + (size_t)s * L_SEQ * NH;
    if (lane < 32) {
        lp[(size_t)(qw + lane) * NH + h] = lsA;
        lp[(size_t)(qw + 32 + lane) * NH + h] = lsB;
    }
#pragma unroll
    for (int n = 0; n < 2; ++n)
#pragma unroll
        for (int r = 0; r < 16; ++r) {
            const int rr = (r & 3) + 8 * (r >> 2) + 4 * hf;
            op[(size_t)(qw + rr) * CDIM + h * HD + n * 32 + l31] = f2bf(oacc0[n][r]);
            op[(size_t)(qw + 32 + rr) * CDIM + h * HD + n * 32 + l31] = f2bf(oacc1[n][r]);
        }
}

// ---------------------------------------------------------------------------
// Combine split-KV partials: out = sum(O_s) / sum(l_s), bf16 (in place s0).
// ---------------------------------------------------------------------------
__global__ __launch_bounds__(256) void combine_splits(const ushort_t* __restrict__ opart,
                                                      const float* __restrict__ lpart,
                                                      ushort_t* __restrict__ out,
                                                      int nsplit) {
    const size_t i4 = ((size_t)blockIdx.x * 256 + threadIdx.x) << 2;
    const int row = (int)(i4 >> 9);
    const int h = (int)((i4 & 511) >> 6);
    float l = 0.0f;
    for (int s = 0; s < nsplit; ++s)
        l += lpart[(size_t)s * L_SEQ * NH + (size_t)row * NH + h];
    const float inv = 1.0f / l;

    float acc[4] = {};
    for (int s = 0; s < nsplit; ++s) {
        ushort_t a[4];
        *reinterpret_cast<uint2*>(a) =
            *reinterpret_cast<const uint2*>(opart + (size_t)s * L_SEQ * CDIM + i4);
#pragma unroll
        for (int j = 0; j < 4; ++j) acc[j] += bf2f(a[j]);
    }
    ushort_t r[4];
#pragma unroll
    for (int j = 0; j < 4; ++j) r[j] = f2bf(acc[j] * inv);
    *reinterpret_cast<uint2*>(out + i4) = *reinterpret_cast<const uint2*>(r);
}

// ---------------------------------------------------------------------------
extern "C" void kernel_launch(void* const* d_in, const int* in_sizes, int n_in,
                              void* d_out, int out_size, void* d_ws, size_t ws_size,
                              hipStream_t stream) {
    const float* x   = (const float*)d_in[0];
    const float* Wq  = (const float*)d_in[1];
    const float* Wk  = (const float*)d_in[2];
    const float* Wv  = (const float*)d_in[3];
    const float* qnw = (const float*)d_in[4];
    const float* knw = (const float*)d_in[5];
    const float* Wo  = (const float*)d_in[6];
    float* out = (float*)d_out;

    char* p = (char*)d_ws;
    ushort_t* opart = (ushort_t*)p;                        // NSPLIT x 4MB bf16
    ushort_t* xb    = opart;                               // phase-1 alias
    ushort_t* abuf  = opart;                               // phase-3 alias
    char* q = p + (size_t)NSPLIT * L_SEQ * CDIM * 2;
    ushort_t* qbuf = (ushort_t*)q;
    ushort_t* kbuf = qbuf + (size_t)L_SEQ * CDIM;
    ushort_t* vtb  = kbuf + (size_t)L_SEQ * NKV * HD;
    ushort_t* wqb  = vtb  + (size_t)L_SEQ * NKV * HD;
    ushort_t* wkb  = wqb  + (size_t)CDIM * CDIM;
    ushort_t* wvb  = wkb  + (size_t)NKV * HD * CDIM;
    ushort_t* wob  = wvb  + (size_t)NKV * HD * CDIM;
    float*    lpart = (float*)(wob + (size_t)CDIM * CDIM);

    const dim3 blk(256);

    // f32 -> bf16 conversions (x + all weights)
    cvt_bf16<<<dim3(2688), blk, 0, stream>>>(x, Wq, Wk, Wv, Wo, xb, wqb, wkb, wvb, wob);

    // Fused QKV projections + RMSNorm + RoPE (128^2 tiles, 192 blocks)
    qkv_gemm128<<<dim3(192), blk, 0, stream>>>(xb, wqb, wkb, wvb, qnw, knw, qbuf, kbuf, vtb);

    // Attention: split-KV x NSPLIT, QR=64 per wave, unnormalized partials
    attn_mfma<<<dim3(L_SEQ / 256, NH, NSPLIT), blk, 0, stream>>>(qbuf, kbuf, vtb, opart, lpart);

    // Combine partials -> bf16 attn out (in place over split 0)
    combine_splits<<<dim3((L_SEQ * CDIM) / (256 * 4)), blk, 0, stream>>>(opart, lpart, abuf, NSPLIT);

    // Output projection (128^2 tiles, f32 out)
    gemm128_wo<<<dim3(CDIM / 128, L_SEQ / 128), blk, 0, stream>>>(abuf, wob, out);
}

// Round 14
// 95.819 us; speedup vs baseline: 1.2208x; 1.2208x over previous
//
#include <hip/hip_runtime.h>
#include <hip/hip_bf16.h>
#include <math.h>

// Problem constants
#define L_SEQ 4096
#define CDIM  512
#define NH    8
#define NKV   2
#define HD    64
#define EPS   1e-6f
// 1/sqrt(64) * log2(e), folded into Q so attn P = exp2(S) directly
#define QSCALE 0.18033688011f
#define NSPLIT 4

using short8 = __attribute__((ext_vector_type(8))) short;
using f32x4  = __attribute__((ext_vector_type(4))) float;
using f32x16 = __attribute__((ext_vector_type(16))) float;
typedef unsigned short ushort_t;

// RNE float -> bf16 bits
__device__ __forceinline__ ushort_t f2bf(float f) {
    union { float f; unsigned u; } c; c.f = f;
    unsigned r = c.u + 0x7FFF + ((c.u >> 16) & 1);
    return (ushort_t)(r >> 16);
}
__device__ __forceinline__ float bf2f(ushort_t u) {
    union { unsigned u; float f; } c; c.u = ((unsigned)u) << 16;
    return c.f;
}

// async global->LDS, 16B per lane; LDS dest = wave-uniform base + lane*16
#define GLOAD_LDS16(g, l)                                                  \
    __builtin_amdgcn_global_load_lds(                                      \
        (const __attribute__((address_space(1))) unsigned int*)(g),        \
        (__attribute__((address_space(3))) unsigned int*)(l), 16, 0, 0)

__device__ __forceinline__ short8 lds_read8(const char* p) {
    return *reinterpret_cast<const short8*>(__builtin_assume_aligned(p, 16));
}

// pack two floats to one u32 of 2 bf16 (lo in low short)
__device__ __forceinline__ unsigned pk_bf16(float lo, float hi) {
    const __hip_bfloat162 h2 = __float22bfloat162_rn(make_float2(lo, hi));
    unsigned w; __builtin_memcpy(&w, &h2, 4);
    return w;
}

// ---------------------------------------------------------------------------
// f32 -> bf16 conversion for x and the 4 weights, PLUS RoPE sin/cos table
// build (one launch: 2688 convert blocks + 512 table blocks).
// rope_tab[pos*32 + i] = (sin, cos)(pos * 10000^(-i/32)).
// ---------------------------------------------------------------------------
__global__ __launch_bounds__(256) void cvt_bf16(const float* __restrict__ x,
                                                const float* __restrict__ wq,
                                                const float* __restrict__ wk,
                                                const float* __restrict__ wv,
                                                const float* __restrict__ wo,
                                                ushort_t* __restrict__ xb,
                                                ushort_t* __restrict__ wqb,
                                                ushort_t* __restrict__ wkb,
                                                ushort_t* __restrict__ wvb,
                                                ushort_t* __restrict__ wob,
                                                float2* __restrict__ rope_tab) {
    const size_t tidg = (size_t)blockIdx.x * 256 + threadIdx.x;
    if (blockIdx.x >= 2688) {
        const int idx = (int)(tidg - (size_t)2688 * 256);   // 0..131071
        const int pos = idx >> 5, i = idx & 31;
        const float invf = exp2f((float)i * -0.41524101186f);
        float sn, cs;
        sincosf((float)pos * invf, &sn, &cs);
        rope_tab[idx] = make_float2(sn, cs);
        return;
    }
    const size_t i = tidg << 2;
    const float* s; ushort_t* d; size_t o;
    if (i < 2097152)      { s = x;  d = xb;  o = i; }
    else if (i < 2359296) { s = wq; d = wqb; o = i - 2097152; }
    else if (i < 2424832) { s = wk; d = wkb; o = i - 2359296; }
    else if (i < 2490368) { s = wv; d = wvb; o = i - 2424832; }
    else                  { s = wo; d = wob; o = i - 2490368; }
    const float4 v = *reinterpret_cast<const float4*>(s + o);
    ushort_t r[4] = { f2bf(v.x), f2bf(v.y), f2bf(v.z), f2bf(v.w) };
    *reinterpret_cast<uint2*>(d + o) = *reinterpret_cast<const uint2*>(r);
}

// ---------------------------------------------------------------------------
// Fused QKV projection (one launch, 768 blocks, 64^2 tiles):
//   bid <  512 : Q = xb * Wq^T   + fused RMSNorm+RoPE (table-driven)
//   bid <  640 : K = xb * Wk^T   + fused RMSNorm+RoPE
//   bid >= 640 : Vt = Wv * xb^T  plain bf16 store
// ---------------------------------------------------------------------------
__global__ __launch_bounds__(256) void qkv_gemm(const ushort_t* __restrict__ xb,
                                                const ushort_t* __restrict__ wqb,
                                                const ushort_t* __restrict__ wkb,
                                                const ushort_t* __restrict__ wvb,
                                                const float* __restrict__ qnw,
                                                const float* __restrict__ knw,
                                                const float2* __restrict__ rope_tab,
                                                ushort_t* __restrict__ qbuf,
                                                ushort_t* __restrict__ kbuf,
                                                ushort_t* __restrict__ vtb) {
    __shared__ char smem[32768];
    short (*As)[4096] = (short(*)[4096])smem;
    short (*Bs)[4096] = (short(*)[4096])(smem + 16384);
    float (*F)[65]    = (float(*)[65])smem;   // aliases As/Bs; used after loop

    const int bid = blockIdx.x;
    int which, m0, n0;
    const ushort_t *A, *B;
    if (bid < 512)      { which = 0; A = xb;  B = wqb; m0 = (bid >> 3) * 64; n0 = (bid & 7) * 64; }
    else if (bid < 640) { which = 1; A = xb;  B = wkb; const int i = bid - 512; m0 = (i >> 1) * 64; n0 = (i & 1) * 64; }
    else                { which = 2; A = wvb; B = xb;  const int i = bid - 640; m0 = (i & 1) * 64; n0 = (i >> 1) * 64; }

    const int tid = threadIdx.x;
    const int w = tid >> 6, lane = tid & 63;
    const int g = lane >> 4, r16 = lane & 15;
    const int wr = w >> 1, wc = w & 1;
    const int r7sw = (r16 & 7) << 4;

    const int lrow = lane >> 3;
    const int swzb = ((lane & 7) ^ lrow) << 4;
    const int c0 = w * 2, c1 = w * 2 + 1;
    const size_t rowK2 = (size_t)CDIM * 2;

    const char* agA = (const char*)A + (size_t)(m0 + c0 * 8 + lrow) * rowK2 + swzb;
    const char* agB = agA + 8 * rowK2;
    const char* bgA = (const char*)B + (size_t)(n0 + c0 * 8 + lrow) * rowK2 + swzb;
    const char* bgB = bgA + 8 * rowK2;

    GLOAD_LDS16(agA, (char*)As[0] + c0 * 1024);
    GLOAD_LDS16(agB, (char*)As[0] + c1 * 1024);
    GLOAD_LDS16(bgA, (char*)Bs[0] + c0 * 1024);
    GLOAD_LDS16(bgB, (char*)Bs[0] + c1 * 1024);
    __syncthreads();

    f32x4 acc[2][2] = {};
    int cur = 0;
    for (int it = 0; it < CDIM / 64; ++it) {
        if (it + 1 < CDIM / 64) {
            const size_t ko = (size_t)(it + 1) * 128;
            char* ad = (char*)As[cur ^ 1];
            char* bd = (char*)Bs[cur ^ 1];
            GLOAD_LDS16(agA + ko, ad + c0 * 1024);
            GLOAD_LDS16(agB + ko, ad + c1 * 1024);
            GLOAD_LDS16(bgA + ko, bd + c0 * 1024);
            GLOAD_LDS16(bgB + ko, bd + c1 * 1024);
        }
        const char* at = (const char*)As[cur];
        const char* bt = (const char*)Bs[cur];

        short8 af[2][2], bfr[2][2];
#pragma unroll
        for (int t = 0; t < 2; ++t)
#pragma unroll
            for (int ks = 0; ks < 2; ++ks) {
                af[t][ks]  = lds_read8(at + (wr * 32 + t * 16 + r16) * 128
                                          + ((ks * 64 + g * 16) ^ r7sw));
                bfr[t][ks] = lds_read8(bt + (wc * 32 + t * 16 + r16) * 128
                                          + ((ks * 64 + g * 16) ^ r7sw));
            }
        __builtin_amdgcn_s_setprio(1);
#pragma unroll
        for (int tm = 0; tm < 2; ++tm)
#pragma unroll
            for (int tn = 0; tn < 2; ++tn)
#pragma unroll
                for (int ks = 0; ks < 2; ++ks)
                    acc[tm][tn] = __builtin_amdgcn_mfma_f32_16x16x32_bf16(
                        af[tm][ks], bfr[tn][ks], acc[tm][tn], 0, 0, 0);
        __builtin_amdgcn_s_setprio(0);

        __syncthreads();
        cur ^= 1;
    }

    if (which == 2) {
#pragma unroll
        for (int tm = 0; tm < 2; ++tm)
#pragma unroll
            for (int tn = 0; tn < 2; ++tn)
#pragma unroll
                for (int jj = 0; jj < 4; ++jj) {
                    const int row = m0 + wr * 32 + tm * 16 + g * 4 + jj;
                    const int col = n0 + wc * 32 + tn * 16 + r16;
                    vtb[(size_t)row * L_SEQ + col] = f2bf(acc[tm][tn][jj]);
                }
        return;
    }

    // ---- fused RMSNorm + RoPE epilogue (which = 0 Q, 1 K) ----
#pragma unroll
    for (int tm = 0; tm < 2; ++tm)
#pragma unroll
        for (int tn = 0; tn < 2; ++tn)
#pragma unroll
            for (int jj = 0; jj < 4; ++jj)
                F[wr * 32 + tm * 16 + g * 4 + jj][wc * 32 + tn * 16 + r16] = acc[tm][tn][jj];
    __syncthreads();

    const float wv_ = (which == 0 ? qnw : knw)[lane];
    const int i31 = lane & 31;
    ushort_t* dst = (which == 0) ? qbuf : kbuf;
    const int ncols = (which == 0) ? (NH * HD) : (NKV * HD);

    for (int rr = 0; rr < 16; ++rr) {
        const int rl = w * 16 + rr;
        const int pos = m0 + rl;
        float x = F[rl][lane];
        float ss = x * x;
#pragma unroll
        for (int off = 32; off; off >>= 1) ss += __shfl_xor(ss, off);
        float xn = x * rsqrtf(ss * (1.0f / 64.0f) + EPS) * wv_;
        float xp = __shfl_xor(xn, 32);
        const float2 sc = rope_tab[pos * 32 + i31];
        float out = (lane < 32) ? (xn * sc.y - xp * sc.x) : (xn * sc.y + xp * sc.x);
        if (which == 0) out *= QSCALE;
        dst[(size_t)pos * ncols + n0 + lane] = f2bf(out);
    }
}

// ---------------------------------------------------------------------------
// bf16 MFMA NT GEMM (used for the Wo projection only). 64^2 tiles.
// ---------------------------------------------------------------------------
template<bool OUT_BF16>
__global__ __launch_bounds__(256) void gemm_bf16_nt(const ushort_t* __restrict__ A,
                                                    const ushort_t* __restrict__ B,
                                                    void* __restrict__ Cv,
                                                    int M, int N, int K) {
    __shared__ short As[2][4096];
    __shared__ short Bs[2][4096];

    const int tid = threadIdx.x;
    const int w = tid >> 6, lane = tid & 63;
    const int g = lane >> 4, r16 = lane & 15;
    const int wr = w >> 1, wc = w & 1;
    const int m0 = blockIdx.y * 64, n0 = blockIdx.x * 64;
    const int r7sw = (r16 & 7) << 4;

    const int lrow = lane >> 3;
    const int swzb = ((lane & 7) ^ lrow) << 4;
    const int c0 = w * 2, c1 = w * 2 + 1;
    const size_t rowK2 = (size_t)K * 2;

    const char* agA = (const char*)A + (size_t)(m0 + c0 * 8 + lrow) * rowK2 + swzb;
    const char* agB = agA + 8 * rowK2;
    const char* bgA = (const char*)B + (size_t)(n0 + c0 * 8 + lrow) * rowK2 + swzb;
    const char* bgB = bgA + 8 * rowK2;

    GLOAD_LDS16(agA, (char*)As[0] + c0 * 1024);
    GLOAD_LDS16(agB, (char*)As[0] + c1 * 1024);
    GLOAD_LDS16(bgA, (char*)Bs[0] + c0 * 1024);
    GLOAD_LDS16(bgB, (char*)Bs[0] + c1 * 1024);
    __syncthreads();

    f32x4 acc[2][2] = {};
    const int NKIT = K >> 6;
    int cur = 0;
    for (int it = 0; it < NKIT; ++it) {
        if (it + 1 < NKIT) {
            const size_t ko = (size_t)(it + 1) * 128;
            char* ad = (char*)As[cur ^ 1];
            char* bd = (char*)Bs[cur ^ 1];
            GLOAD_LDS16(agA + ko, ad + c0 * 1024);
            GLOAD_LDS16(agB + ko, ad + c1 * 1024);
            GLOAD_LDS16(bgA + ko, bd + c0 * 1024);
            GLOAD_LDS16(bgB + ko, bd + c1 * 1024);
        }
        const char* at = (const char*)As[cur];
        const char* bt = (const char*)Bs[cur];

        short8 af[2][2], bfr[2][2];
#pragma unroll
        for (int t = 0; t < 2; ++t)
#pragma unroll
            for (int ks = 0; ks < 2; ++ks) {
                af[t][ks]  = lds_read8(at + (wr * 32 + t * 16 + r16) * 128
                                          + ((ks * 64 + g * 16) ^ r7sw));
                bfr[t][ks] = lds_read8(bt + (wc * 32 + t * 16 + r16) * 128
                                          + ((ks * 64 + g * 16) ^ r7sw));
            }
        __builtin_amdgcn_s_setprio(1);
#pragma unroll
        for (int tm = 0; tm < 2; ++tm)
#pragma unroll
            for (int tn = 0; tn < 2; ++tn)
#pragma unroll
                for (int ks = 0; ks < 2; ++ks)
                    acc[tm][tn] = __builtin_amdgcn_mfma_f32_16x16x32_bf16(
                        af[tm][ks], bfr[tn][ks], acc[tm][tn], 0, 0, 0);
        __builtin_amdgcn_s_setprio(0);

        __syncthreads();
        cur ^= 1;
    }

#pragma unroll
    for (int tm = 0; tm < 2; ++tm)
#pragma unroll
        for (int tn = 0; tn < 2; ++tn)
#pragma unroll
            for (int jj = 0; jj < 4; ++jj) {
                const int row = m0 + wr * 32 + tm * 16 + g * 4 + jj;
                const int col = n0 + wc * 32 + tn * 16 + r16;
                if (OUT_BF16)
                    ((ushort_t*)Cv)[(size_t)row * N + col] = f2bf(acc[tm][tn][jj]);
                else
                    ((float*)Cv)[(size_t)row * N + col] = acc[tm][tn][jj];
            }
}

// ---------------------------------------------------------------------------
// Flash attention (QR=64, swapped QK^T 32x32, lane-local softmax,
// permlane32_swap, exp2f builtins). nsplit via gridDim.z.
// ---------------------------------------------------------------------------
__global__ __launch_bounds__(256, 2) void attn_mfma(const ushort_t* __restrict__ qb,
                                                    const ushort_t* __restrict__ kb,
                                                    const ushort_t* __restrict__ vtb,
                                                    ushort_t* __restrict__ opart,
                                                    float* __restrict__ lpart) {
    __shared__ short Ks[2][4096];
    __shared__ short Vs[2][4096];

    const int tid = threadIdx.x;
    const int w = tid >> 6, lane = tid & 63;
    const int l31 = lane & 31, hf = lane >> 5;
    const int h = blockIdx.y, hkv = h >> 2;
    const int s = blockIdx.z;
    const int kvspan = L_SEQ / gridDim.z;
    const int kvb = s * kvspan;
    const int qw = blockIdx.x * 256 + w * 64;
    const int swz = (lane & 7) << 4;

    const int lrow = lane >> 3;
    const int swzb = ((lane & 7) ^ lrow) << 4;
    const int c0 = w * 2, c1 = w * 2 + 1;

    const char* kgA = (const char*)kb + (size_t)(kvb + c0 * 8 + lrow) * (NKV * HD * 2)
                      + hkv * (HD * 2) + swzb;
    const char* kgB = kgA + 8 * (NKV * HD * 2);
    const char* vgA = (const char*)vtb + (size_t)(hkv * HD + c0 * 8 + lrow) * (L_SEQ * 2)
                      + (size_t)kvb * 2 + swzb;
    const char* vgB = vgA + 8 * (size_t)(L_SEQ * 2);

    short8 qf0[4], qf1[4];
#pragma unroll
    for (int ks = 0; ks < 4; ++ks) {
        qf0[ks] = *reinterpret_cast<const short8*>(
            &qb[(size_t)(qw + l31) * CDIM + h * HD + ks * 16 + hf * 8]);
        qf1[ks] = *reinterpret_cast<const short8*>(
            &qb[(size_t)(qw + 32 + l31) * CDIM + h * HD + ks * 16 + hf * 8]);
    }

    GLOAD_LDS16(kgA, (char*)Ks[0] + c0 * 1024);
    GLOAD_LDS16(kgB, (char*)Ks[0] + c1 * 1024);
    GLOAD_LDS16(vgA, (char*)Vs[0] + c0 * 1024);
    GLOAD_LDS16(vgB, (char*)Vs[0] + c1 * 1024);
    __syncthreads();

    f32x16 oacc0[2] = {}, oacc1[2] = {};
    float ls0[2] = {}, ls1[2] = {};

    int cur = 0;
    const int nit = kvspan >> 6;
    for (int it = 0; it < nit; ++it) {
        if (it + 1 < nit) {
            const size_t ko = (size_t)(it + 1) * 64 * (NKV * HD * 2);
            const size_t vo = (size_t)(it + 1) * 128;
            char* kd = (char*)Ks[cur ^ 1];
            char* vd = (char*)Vs[cur ^ 1];
            GLOAD_LDS16(kgA + ko, kd + c0 * 1024);
            GLOAD_LDS16(kgB + ko, kd + c1 * 1024);
            GLOAD_LDS16(vgA + vo, vd + c0 * 1024);
            GLOAD_LDS16(vgB + vo, vd + c1 * 1024);
        }

        const char* kt = (const char*)Ks[cur];
        const char* vt = (const char*)Vs[cur];

#pragma unroll
        for (int sub = 0; sub < 2; ++sub) {
            f32x16 s0 = {}, s1 = {};
            __builtin_amdgcn_s_setprio(1);
#pragma unroll
            for (int ks = 0; ks < 4; ++ks) {
                const short8 kfr = lds_read8(
                    kt + (sub * 32 + l31) * 128 + ((ks * 32 + hf * 16) ^ swz));
                s0 = __builtin_amdgcn_mfma_f32_32x32x16_bf16(kfr, qf0[ks], s0, 0, 0, 0);
                s1 = __builtin_amdgcn_mfma_f32_32x32x16_bf16(kfr, qf1[ks], s1, 0, 0, 0);
            }
            __builtin_amdgcn_s_setprio(0);

            unsigned pk0[8], pk1[8];
#pragma unroll
            for (int r2 = 0; r2 < 8; ++r2) {
                const float x0 = exp2f(s0[2 * r2]), y0 = exp2f(s0[2 * r2 + 1]);
                const float x1 = exp2f(s1[2 * r2]), y1 = exp2f(s1[2 * r2 + 1]);
                ls0[r2 & 1] += x0 + y0;
                ls1[r2 & 1] += x1 + y1;
                pk0[r2] = pk_bf16(x0, y0);
                pk1[r2] = pk_bf16(x1, y1);
            }

            short8 pf0[2], pf1[2];
#pragma unroll
            for (int kkl = 0; kkl < 2; ++kkl) {
                auto a0 = __builtin_amdgcn_permlane32_swap(pk0[kkl * 4 + 0], pk0[kkl * 4 + 2], false, false);
                auto a1 = __builtin_amdgcn_permlane32_swap(pk0[kkl * 4 + 1], pk0[kkl * 4 + 3], false, false);
                auto b0 = __builtin_amdgcn_permlane32_swap(pk1[kkl * 4 + 0], pk1[kkl * 4 + 2], false, false);
                auto b1 = __builtin_amdgcn_permlane32_swap(pk1[kkl * 4 + 1], pk1[kkl * 4 + 3], false, false);
                union { unsigned u[4]; short8 s8; } u0, u1;
                u0.u[0] = a0[0]; u0.u[1] = a1[0]; u0.u[2] = a0[1]; u0.u[3] = a1[1];
                u1.u[0] = b0[0]; u1.u[1] = b1[0]; u1.u[2] = b0[1]; u1.u[3] = b1[1];
                pf0[kkl] = u0.s8; pf1[kkl] = u1.s8;
            }

            __builtin_amdgcn_s_setprio(1);
#pragma unroll
            for (int n = 0; n < 2; ++n) {
#pragma unroll
                for (int kkl = 0; kkl < 2; ++kkl) {
                    const short8 vf = lds_read8(
                        vt + (n * 32 + l31) * 128 + (((sub * 2 + kkl) * 32 + hf * 16) ^ swz));
                    oacc0[n] = __builtin_amdgcn_mfma_f32_32x32x16_bf16(pf0[kkl], vf, oacc0[n], 0, 0, 0);
                    oacc1[n] = __builtin_amdgcn_mfma_f32_32x32x16_bf16(pf1[kkl], vf, oacc1[n], 0, 0, 0);
                }
            }
            __builtin_amdgcn_s_setprio(0);
        }

        __syncthreads();
        cur ^= 1;
    }

    float lsA = ls0[0] + ls0[1];
    float lsB = ls1[0] + ls1[1];
    lsA += __shfl_xor(lsA, 32);
    lsB += __shfl_xor(lsB, 32);
    ushort_t* op = opart + (size_t)s * L_SEQ * CDIM;
    float* lp = lpart + (size_t)s * L_SEQ * NH;
    if (lane < 32) {
        lp[(size_t)(qw + lane) * NH + h] = lsA;
        lp[(size_t)(qw + 32 + lane) * NH + h] = lsB;
    }
#pragma unroll
    for (int n = 0; n < 2; ++n)
#pragma unroll
        for (int r = 0; r < 16; ++r) {
            const int rr = (r & 3) + 8 * (r >> 2) + 4 * hf;
            op[(size_t)(qw + rr) * CDIM + h * HD + n * 32 + l31] = f2bf(oacc0[n][r]);
            op[(size_t)(qw + 32 + rr) * CDIM + h * HD + n * 32 + l31] = f2bf(oacc1[n][r]);
        }
}

// ---------------------------------------------------------------------------
// Combine split-KV partials: out = sum(O_s) / sum(l_s), bf16 (in place s0).
// ---------------------------------------------------------------------------
__global__ __launch_bounds__(256) void combine_splits(const ushort_t* __restrict__ opart,
                                                      const float* __restrict__ lpart,
                                                      ushort_t* __restrict__ out,
                                                      int nsplit) {
    const size_t i4 = ((size_t)blockIdx.x * 256 + threadIdx.x) << 2;
    const int row = (int)(i4 >> 9);
    const int h = (int)((i4 & 511) >> 6);
    float l = 0.0f;
    for (int s = 0; s < nsplit; ++s)
        l += lpart[(size_t)s * L_SEQ * NH + (size_t)row * NH + h];
    const float inv = 1.0f / l;

    float acc[4] = {};
    for (int s = 0; s < nsplit; ++s) {
        ushort_t a[4];
        *reinterpret_cast<uint2*>(a) =
            *reinterpret_cast<const uint2*>(opart + (size_t)s * L_SEQ * CDIM + i4);
#pragma unroll
        for (int j = 0; j < 4; ++j) acc[j] += bf2f(a[j]);
    }
    ushort_t r[4];
#pragma unroll
    for (int j = 0; j < 4; ++j) r[j] = f2bf(acc[j] * inv);
    *reinterpret_cast<uint2*>(out + i4) = *reinterpret_cast<const uint2*>(r);
}

// ---------------------------------------------------------------------------
extern "C" void kernel_launch(void* const* d_in, const int* in_sizes, int n_in,
                              void* d_out, int out_size, void* d_ws, size_t ws_size,
                              hipStream_t stream) {
    const float* x   = (const float*)d_in[0];
    const float* Wq  = (const float*)d_in[1];
    const float* Wk  = (const float*)d_in[2];
    const float* Wv  = (const float*)d_in[3];
    const float* qnw = (const float*)d_in[4];
    const float* knw = (const float*)d_in[5];
    const float* Wo  = (const float*)d_in[6];
    float* out = (float*)d_out;

    char* p = (char*)d_ws;
    ushort_t* opart = (ushort_t*)p;                        // NSPLIT x 4MB bf16
    ushort_t* xb    = opart;                               // phase-1 alias
    ushort_t* abuf  = opart;                               // phase-3 alias
    char* q = p + (size_t)NSPLIT * L_SEQ * CDIM * 2;
    ushort_t* qbuf = (ushort_t*)q;
    ushort_t* kbuf = qbuf + (size_t)L_SEQ * CDIM;
    ushort_t* vtb  = kbuf + (size_t)L_SEQ * NKV * HD;
    ushort_t* wqb  = vtb  + (size_t)L_SEQ * NKV * HD;
    ushort_t* wkb  = wqb  + (size_t)CDIM * CDIM;
    ushort_t* wvb  = wkb  + (size_t)NKV * HD * CDIM;
    ushort_t* wob  = wvb  + (size_t)NKV * HD * CDIM;
    float*    lpart = (float*)(wob + (size_t)CDIM * CDIM);           // 512 KB
    float2*   rope_tab = (float2*)(lpart + (size_t)NSPLIT * L_SEQ * NH); // 1 MB

    const dim3 blk(256);

    // f32 -> bf16 conversions (x + all weights) + RoPE sin/cos table
    cvt_bf16<<<dim3(3200), blk, 0, stream>>>(x, Wq, Wk, Wv, Wo,
                                             xb, wqb, wkb, wvb, wob, rope_tab);

    // Fused QKV projections + RMSNorm + RoPE (table-driven, 768 blocks)
    qkv_gemm<<<dim3(768), blk, 0, stream>>>(xb, wqb, wkb, wvb, qnw, knw,
                                            rope_tab, qbuf, kbuf, vtb);

    // Attention: split-KV x NSPLIT, QR=64 per wave, unnormalized partials
    attn_mfma<<<dim3(L_SEQ / 256, NH, NSPLIT), blk, 0, stream>>>(qbuf, kbuf, vtb, opart, lpart);

    // Combine partials -> bf16 attn out (in place over split 0)
    combine_splits<<<dim3((L_SEQ * CDIM) / (256 * 4)), blk, 0, stream>>>(opart, lpart, abuf, NSPLIT);

    // Output projection (64^2 tiles, f32 out)
    gemm_bf16_nt<false><<<dim3(8, 64), blk, 0, stream>>>(abuf, wob, out, L_SEQ, CDIM, CDIM);
}

// Round 15
// 93.781 us; speedup vs baseline: 1.2473x; 1.0217x over previous
//
#include <hip/hip_runtime.h>
#include <hip/hip_bf16.h>
#include <math.h>

// Problem constants
#define L_SEQ 4096
#define CDIM  512
#define NH    8
#define NKV   2
#define HD    64
#define EPS   1e-6f
// 1/sqrt(64) * log2(e), folded into Q so attn P = exp2(S) directly
#define QSCALE 0.18033688011f
#define NSPLIT 4

using short8 = __attribute__((ext_vector_type(8))) short;
using f32x4  = __attribute__((ext_vector_type(4))) float;
using f32x16 = __attribute__((ext_vector_type(16))) float;
typedef unsigned short ushort_t;

// RNE float -> bf16 bits
__device__ __forceinline__ ushort_t f2bf(float f) {
    union { float f; unsigned u; } c; c.f = f;
    unsigned r = c.u + 0x7FFF + ((c.u >> 16) & 1);
    return (ushort_t)(r >> 16);
}
__device__ __forceinline__ float bf2f(ushort_t u) {
    union { unsigned u; float f; } c; c.u = ((unsigned)u) << 16;
    return c.f;
}

// async global->LDS, 16B per lane; LDS dest = wave-uniform base + lane*16
#define GLOAD_LDS16(g, l)                                                  \
    __builtin_amdgcn_global_load_lds(                                      \
        (const __attribute__((address_space(1))) unsigned int*)(g),        \
        (__attribute__((address_space(3))) unsigned int*)(l), 16, 0, 0)

__device__ __forceinline__ short8 lds_read8(const char* p) {
    return *reinterpret_cast<const short8*>(__builtin_assume_aligned(p, 16));
}

// pack two floats to one u32 of 2 bf16 (lo in low short)
__device__ __forceinline__ unsigned pk_bf16(float lo, float hi) {
    const __hip_bfloat162 h2 = __float22bfloat162_rn(make_float2(lo, hi));
    unsigned w; __builtin_memcpy(&w, &h2, 4);
    return w;
}

// ---------------------------------------------------------------------------
// f32 -> bf16 conversion for x and the 4 weights, PLUS RoPE sin/cos table
// build (one launch: 2688 convert blocks + 512 table blocks).
// rope_tab[pos*32 + i] = (sin, cos)(pos * 10000^(-i/32)).
// ---------------------------------------------------------------------------
__global__ __launch_bounds__(256) void cvt_bf16(const float* __restrict__ x,
                                                const float* __restrict__ wq,
                                                const float* __restrict__ wk,
                                                const float* __restrict__ wv,
                                                const float* __restrict__ wo,
                                                ushort_t* __restrict__ xb,
                                                ushort_t* __restrict__ wqb,
                                                ushort_t* __restrict__ wkb,
                                                ushort_t* __restrict__ wvb,
                                                ushort_t* __restrict__ wob,
                                                float2* __restrict__ rope_tab) {
    const size_t tidg = (size_t)blockIdx.x * 256 + threadIdx.x;
    if (blockIdx.x >= 2688) {
        const int idx = (int)(tidg - (size_t)2688 * 256);   // 0..131071
        const int pos = idx >> 5, i = idx & 31;
        const float invf = exp2f((float)i * -0.41524101186f);
        float sn, cs;
        sincosf((float)pos * invf, &sn, &cs);
        rope_tab[idx] = make_float2(sn, cs);
        return;
    }
    const size_t i = tidg << 2;
    const float* s; ushort_t* d; size_t o;
    if (i < 2097152)      { s = x;  d = xb;  o = i; }
    else if (i < 2359296) { s = wq; d = wqb; o = i - 2097152; }
    else if (i < 2424832) { s = wk; d = wkb; o = i - 2359296; }
    else if (i < 2490368) { s = wv; d = wvb; o = i - 2424832; }
    else                  { s = wo; d = wob; o = i - 2490368; }
    const float4 v = *reinterpret_cast<const float4*>(s + o);
    ushort_t r[4] = { f2bf(v.x), f2bf(v.y), f2bf(v.z), f2bf(v.w) };
    *reinterpret_cast<uint2*>(d + o) = *reinterpret_cast<const uint2*>(r);
}

// ---------------------------------------------------------------------------
// Fused QKV projection (one launch, 768 blocks, 64^2 tiles):
//   bid <  512 : Q = xb * Wq^T   + fused RMSNorm+RoPE (table-driven)
//   bid <  640 : K = xb * Wk^T   + fused RMSNorm+RoPE
//   bid >= 640 : Vt = Wv * xb^T  plain bf16 store
// ---------------------------------------------------------------------------
__global__ __launch_bounds__(256) void qkv_gemm(const ushort_t* __restrict__ xb,
                                                const ushort_t* __restrict__ wqb,
                                                const ushort_t* __restrict__ wkb,
                                                const ushort_t* __restrict__ wvb,
                                                const float* __restrict__ qnw,
                                                const float* __restrict__ knw,
                                                const float2* __restrict__ rope_tab,
                                                ushort_t* __restrict__ qbuf,
                                                ushort_t* __restrict__ kbuf,
                                                ushort_t* __restrict__ vtb) {
    __shared__ char smem[32768];
    short (*As)[4096] = (short(*)[4096])smem;
    short (*Bs)[4096] = (short(*)[4096])(smem + 16384);
    float (*F)[65]    = (float(*)[65])smem;   // aliases As/Bs; used after loop

    const int bid = blockIdx.x;
    int which, m0, n0;
    const ushort_t *A, *B;
    if (bid < 512)      { which = 0; A = xb;  B = wqb; m0 = (bid >> 3) * 64; n0 = (bid & 7) * 64; }
    else if (bid < 640) { which = 1; A = xb;  B = wkb; const int i = bid - 512; m0 = (i >> 1) * 64; n0 = (i & 1) * 64; }
    else                { which = 2; A = wvb; B = xb;  const int i = bid - 640; m0 = (i & 1) * 64; n0 = (i >> 1) * 64; }

    const int tid = threadIdx.x;
    const int w = tid >> 6, lane = tid & 63;
    const int g = lane >> 4, r16 = lane & 15;
    const int wr = w >> 1, wc = w & 1;
    const int r7sw = (r16 & 7) << 4;

    const int lrow = lane >> 3;
    const int swzb = ((lane & 7) ^ lrow) << 4;
    const int c0 = w * 2, c1 = w * 2 + 1;
    const size_t rowK2 = (size_t)CDIM * 2;

    const char* agA = (const char*)A + (size_t)(m0 + c0 * 8 + lrow) * rowK2 + swzb;
    const char* agB = agA + 8 * rowK2;
    const char* bgA = (const char*)B + (size_t)(n0 + c0 * 8 + lrow) * rowK2 + swzb;
    const char* bgB = bgA + 8 * rowK2;

    GLOAD_LDS16(agA, (char*)As[0] + c0 * 1024);
    GLOAD_LDS16(agB, (char*)As[0] + c1 * 1024);
    GLOAD_LDS16(bgA, (char*)Bs[0] + c0 * 1024);
    GLOAD_LDS16(bgB, (char*)Bs[0] + c1 * 1024);
    __syncthreads();

    f32x4 acc[2][2] = {};
    int cur = 0;
    for (int it = 0; it < CDIM / 64; ++it) {
        if (it + 1 < CDIM / 64) {
            const size_t ko = (size_t)(it + 1) * 128;
            char* ad = (char*)As[cur ^ 1];
            char* bd = (char*)Bs[cur ^ 1];
            GLOAD_LDS16(agA + ko, ad + c0 * 1024);
            GLOAD_LDS16(agB + ko, ad + c1 * 1024);
            GLOAD_LDS16(bgA + ko, bd + c0 * 1024);
            GLOAD_LDS16(bgB + ko, bd + c1 * 1024);
        }
        const char* at = (const char*)As[cur];
        const char* bt = (const char*)Bs[cur];

        short8 af[2][2], bfr[2][2];
#pragma unroll
        for (int t = 0; t < 2; ++t)
#pragma unroll
            for (int ks = 0; ks < 2; ++ks) {
                af[t][ks]  = lds_read8(at + (wr * 32 + t * 16 + r16) * 128
                                          + ((ks * 64 + g * 16) ^ r7sw));
                bfr[t][ks] = lds_read8(bt + (wc * 32 + t * 16 + r16) * 128
                                          + ((ks * 64 + g * 16) ^ r7sw));
            }
        __builtin_amdgcn_s_setprio(1);
#pragma unroll
        for (int tm = 0; tm < 2; ++tm)
#pragma unroll
            for (int tn = 0; tn < 2; ++tn)
#pragma unroll
                for (int ks = 0; ks < 2; ++ks)
                    acc[tm][tn] = __builtin_amdgcn_mfma_f32_16x16x32_bf16(
                        af[tm][ks], bfr[tn][ks], acc[tm][tn], 0, 0, 0);
        __builtin_amdgcn_s_setprio(0);

        __syncthreads();
        cur ^= 1;
    }

    if (which == 2) {
#pragma unroll
        for (int tm = 0; tm < 2; ++tm)
#pragma unroll
            for (int tn = 0; tn < 2; ++tn)
#pragma unroll
                for (int jj = 0; jj < 4; ++jj) {
                    const int row = m0 + wr * 32 + tm * 16 + g * 4 + jj;
                    const int col = n0 + wc * 32 + tn * 16 + r16;
                    vtb[(size_t)row * L_SEQ + col] = f2bf(acc[tm][tn][jj]);
                }
        return;
    }

    // ---- fused RMSNorm + RoPE epilogue (which = 0 Q, 1 K) ----
#pragma unroll
    for (int tm = 0; tm < 2; ++tm)
#pragma unroll
        for (int tn = 0; tn < 2; ++tn)
#pragma unroll
            for (int jj = 0; jj < 4; ++jj)
                F[wr * 32 + tm * 16 + g * 4 + jj][wc * 32 + tn * 16 + r16] = acc[tm][tn][jj];
    __syncthreads();

    const float wv_ = (which == 0 ? qnw : knw)[lane];
    const int i31 = lane & 31;
    ushort_t* dst = (which == 0) ? qbuf : kbuf;
    const int ncols = (which == 0) ? (NH * HD) : (NKV * HD);

    for (int rr = 0; rr < 16; ++rr) {
        const int rl = w * 16 + rr;
        const int pos = m0 + rl;
        float x = F[rl][lane];
        float ss = x * x;
#pragma unroll
        for (int off = 32; off; off >>= 1) ss += __shfl_xor(ss, off);
        float xn = x * rsqrtf(ss * (1.0f / 64.0f) + EPS) * wv_;
        float xp = __shfl_xor(xn, 32);
        const float2 sc = rope_tab[pos * 32 + i31];
        float out = (lane < 32) ? (xn * sc.y - xp * sc.x) : (xn * sc.y + xp * sc.x);
        if (which == 0) out *= QSCALE;
        dst[(size_t)pos * ncols + n0 + lane] = f2bf(out);
    }
}

// ---------------------------------------------------------------------------
// bf16 MFMA NT GEMM (used for the Wo projection only). 64^2 tiles.
// ---------------------------------------------------------------------------
template<bool OUT_BF16>
__global__ __launch_bounds__(256) void gemm_bf16_nt(const ushort_t* __restrict__ A,
                                                    const ushort_t* __restrict__ B,
                                                    void* __restrict__ Cv,
                                                    int M, int N, int K) {
    __shared__ short As[2][4096];
    __shared__ short Bs[2][4096];

    const int tid = threadIdx.x;
    const int w = tid >> 6, lane = tid & 63;
    const int g = lane >> 4, r16 = lane & 15;
    const int wr = w >> 1, wc = w & 1;
    const int m0 = blockIdx.y * 64, n0 = blockIdx.x * 64;
    const int r7sw = (r16 & 7) << 4;

    const int lrow = lane >> 3;
    const int swzb = ((lane & 7) ^ lrow) << 4;
    const int c0 = w * 2, c1 = w * 2 + 1;
    const size_t rowK2 = (size_t)K * 2;

    const char* agA = (const char*)A + (size_t)(m0 + c0 * 8 + lrow) * rowK2 + swzb;
    const char* agB = agA + 8 * rowK2;
    const char* bgA = (const char*)B + (size_t)(n0 + c0 * 8 + lrow) * rowK2 + swzb;
    const char* bgB = bgA + 8 * rowK2;

    GLOAD_LDS16(agA, (char*)As[0] + c0 * 1024);
    GLOAD_LDS16(agB, (char*)As[0] + c1 * 1024);
    GLOAD_LDS16(bgA, (char*)Bs[0] + c0 * 1024);
    GLOAD_LDS16(bgB, (char*)Bs[0] + c1 * 1024);
    __syncthreads();

    f32x4 acc[2][2] = {};
    const int NKIT = K >> 6;
    int cur = 0;
    for (int it = 0; it < NKIT; ++it) {
        if (it + 1 < NKIT) {
            const size_t ko = (size_t)(it + 1) * 128;
            char* ad = (char*)As[cur ^ 1];
            char* bd = (char*)Bs[cur ^ 1];
            GLOAD_LDS16(agA + ko, ad + c0 * 1024);
            GLOAD_LDS16(agB + ko, ad + c1 * 1024);
            GLOAD_LDS16(bgA + ko, bd + c0 * 1024);
            GLOAD_LDS16(bgB + ko, bd + c1 * 1024);
        }
        const char* at = (const char*)As[cur];
        const char* bt = (const char*)Bs[cur];

        short8 af[2][2], bfr[2][2];
#pragma unroll
        for (int t = 0; t < 2; ++t)
#pragma unroll
            for (int ks = 0; ks < 2; ++ks) {
                af[t][ks]  = lds_read8(at + (wr * 32 + t * 16 + r16) * 128
                                          + ((ks * 64 + g * 16) ^ r7sw));
                bfr[t][ks] = lds_read8(bt + (wc * 32 + t * 16 + r16) * 128
                                          + ((ks * 64 + g * 16) ^ r7sw));
            }
        __builtin_amdgcn_s_setprio(1);
#pragma unroll
        for (int tm = 0; tm < 2; ++tm)
#pragma unroll
            for (int tn = 0; tn < 2; ++tn)
#pragma unroll
                for (int ks = 0; ks < 2; ++ks)
                    acc[tm][tn] = __builtin_amdgcn_mfma_f32_16x16x32_bf16(
                        af[tm][ks], bfr[tn][ks], acc[tm][tn], 0, 0, 0);
        __builtin_amdgcn_s_setprio(0);

        __syncthreads();
        cur ^= 1;
    }

#pragma unroll
    for (int tm = 0; tm < 2; ++tm)
#pragma unroll
        for (int tn = 0; tn < 2; ++tn)
#pragma unroll
            for (int jj = 0; jj < 4; ++jj) {
                const int row = m0 + wr * 32 + tm * 16 + g * 4 + jj;
                const int col = n0 + wc * 32 + tn * 16 + r16;
                if (OUT_BF16)
                    ((ushort_t*)Cv)[(size_t)row * N + col] = f2bf(acc[tm][tn][jj]);
                else
                    ((float*)Cv)[(size_t)row * N + col] = acc[tm][tn][jj];
            }
}

// ---------------------------------------------------------------------------
// Flash attention (QR=64, swapped QK^T 32x32, lane-local softmax,
// permlane32_swap, exp2f). NO s_setprio: with 2 waves/SIMD alternating
// prio-1 MFMA and prio-0 VALU phases, setprio starves the VALU-phase wave
// and serializes phases ACROSS waves (m190-class regression) — A/B probe.
// ---------------------------------------------------------------------------
__global__ __launch_bounds__(256, 2) void attn_mfma(const ushort_t* __restrict__ qb,
                                                    const ushort_t* __restrict__ kb,
                                                    const ushort_t* __restrict__ vtb,
                                                    ushort_t* __restrict__ opart,
                                                    float* __restrict__ lpart) {
    __shared__ short Ks[2][4096];
    __shared__ short Vs[2][4096];

    const int tid = threadIdx.x;
    const int w = tid >> 6, lane = tid & 63;
    const int l31 = lane & 31, hf = lane >> 5;
    const int h = blockIdx.y, hkv = h >> 2;
    const int s = blockIdx.z;
    const int kvspan = L_SEQ / gridDim.z;
    const int kvb = s * kvspan;
    const int qw = blockIdx.x * 256 + w * 64;
    const int swz = (lane & 7) << 4;

    const int lrow = lane >> 3;
    const int swzb = ((lane & 7) ^ lrow) << 4;
    const int c0 = w * 2, c1 = w * 2 + 1;

    const char* kgA = (const char*)kb + (size_t)(kvb + c0 * 8 + lrow) * (NKV * HD * 2)
                      + hkv * (HD * 2) + swzb;
    const char* kgB = kgA + 8 * (NKV * HD * 2);
    const char* vgA = (const char*)vtb + (size_t)(hkv * HD + c0 * 8 + lrow) * (L_SEQ * 2)
                      + (size_t)kvb * 2 + swzb;
    const char* vgB = vgA + 8 * (size_t)(L_SEQ * 2);

    short8 qf0[4], qf1[4];
#pragma unroll
    for (int ks = 0; ks < 4; ++ks) {
        qf0[ks] = *reinterpret_cast<const short8*>(
            &qb[(size_t)(qw + l31) * CDIM + h * HD + ks * 16 + hf * 8]);
        qf1[ks] = *reinterpret_cast<const short8*>(
            &qb[(size_t)(qw + 32 + l31) * CDIM + h * HD + ks * 16 + hf * 8]);
    }

    GLOAD_LDS16(kgA, (char*)Ks[0] + c0 * 1024);
    GLOAD_LDS16(kgB, (char*)Ks[0] + c1 * 1024);
    GLOAD_LDS16(vgA, (char*)Vs[0] + c0 * 1024);
    GLOAD_LDS16(vgB, (char*)Vs[0] + c1 * 1024);
    __syncthreads();

    f32x16 oacc0[2] = {}, oacc1[2] = {};
    float ls0[2] = {}, ls1[2] = {};

    int cur = 0;
    const int nit = kvspan >> 6;
    for (int it = 0; it < nit; ++it) {
        if (it + 1 < nit) {
            const size_t ko = (size_t)(it + 1) * 64 * (NKV * HD * 2);
            const size_t vo = (size_t)(it + 1) * 128;
            char* kd = (char*)Ks[cur ^ 1];
            char* vd = (char*)Vs[cur ^ 1];
            GLOAD_LDS16(kgA + ko, kd + c0 * 1024);
            GLOAD_LDS16(kgB + ko, kd + c1 * 1024);
            GLOAD_LDS16(vgA + vo, vd + c0 * 1024);
            GLOAD_LDS16(vgB + vo, vd + c1 * 1024);
        }

        const char* kt = (const char*)Ks[cur];
        const char* vt = (const char*)Vs[cur];

#pragma unroll
        for (int sub = 0; sub < 2; ++sub) {
            f32x16 s0 = {}, s1 = {};
#pragma unroll
            for (int ks = 0; ks < 4; ++ks) {
                const short8 kfr = lds_read8(
                    kt + (sub * 32 + l31) * 128 + ((ks * 32 + hf * 16) ^ swz));
                s0 = __builtin_amdgcn_mfma_f32_32x32x16_bf16(kfr, qf0[ks], s0, 0, 0, 0);
                s1 = __builtin_amdgcn_mfma_f32_32x32x16_bf16(kfr, qf1[ks], s1, 0, 0, 0);
            }

            unsigned pk0[8], pk1[8];
#pragma unroll
            for (int r2 = 0; r2 < 8; ++r2) {
                const float x0 = exp2f(s0[2 * r2]), y0 = exp2f(s0[2 * r2 + 1]);
                const float x1 = exp2f(s1[2 * r2]), y1 = exp2f(s1[2 * r2 + 1]);
                ls0[r2 & 1] += x0 + y0;
                ls1[r2 & 1] += x1 + y1;
                pk0[r2] = pk_bf16(x0, y0);
                pk1[r2] = pk_bf16(x1, y1);
            }

            short8 pf0[2], pf1[2];
#pragma unroll
            for (int kkl = 0; kkl < 2; ++kkl) {
                auto a0 = __builtin_amdgcn_permlane32_swap(pk0[kkl * 4 + 0], pk0[kkl * 4 + 2], false, false);
                auto a1 = __builtin_amdgcn_permlane32_swap(pk0[kkl * 4 + 1], pk0[kkl * 4 + 3], false, false);
                auto b0 = __builtin_amdgcn_permlane32_swap(pk1[kkl * 4 + 0], pk1[kkl * 4 + 2], false, false);
                auto b1 = __builtin_amdgcn_permlane32_swap(pk1[kkl * 4 + 1], pk1[kkl * 4 + 3], false, false);
                union { unsigned u[4]; short8 s8; } u0, u1;
                u0.u[0] = a0[0]; u0.u[1] = a1[0]; u0.u[2] = a0[1]; u0.u[3] = a1[1];
                u1.u[0] = b0[0]; u1.u[1] = b1[0]; u1.u[2] = b0[1]; u1.u[3] = b1[1];
                pf0[kkl] = u0.s8; pf1[kkl] = u1.s8;
            }

#pragma unroll
            for (int n = 0; n < 2; ++n) {
#pragma unroll
                for (int kkl = 0; kkl < 2; ++kkl) {
                    const short8 vf = lds_read8(
                        vt + (n * 32 + l31) * 128 + (((sub * 2 + kkl) * 32 + hf * 16) ^ swz));
                    oacc0[n] = __builtin_amdgcn_mfma_f32_32x32x16_bf16(pf0[kkl], vf, oacc0[n], 0, 0, 0);
                    oacc1[n] = __builtin_amdgcn_mfma_f32_32x32x16_bf16(pf1[kkl], vf, oacc1[n], 0, 0, 0);
                }
            }
        }

        __syncthreads();
        cur ^= 1;
    }

    float lsA = ls0[0] + ls0[1];
    float lsB = ls1[0] + ls1[1];
    lsA += __shfl_xor(lsA, 32);
    lsB += __shfl_xor(lsB, 32);
    ushort_t* op = opart + (size_t)s * L_SEQ * CDIM;
    float* lp = lpart + (size_t)s * L_SEQ * NH;
    if (lane < 32) {
        lp[(size_t)(qw + lane) * NH + h] = lsA;
        lp[(size_t)(qw + 32 + lane) * NH + h] = lsB;
    }
#pragma unroll
    for (int n = 0; n < 2; ++n)
#pragma unroll
        for (int r = 0; r < 16; ++r) {
            const int rr = (r & 3) + 8 * (r >> 2) + 4 * hf;
            op[(size_t)(qw + rr) * CDIM + h * HD + n * 32 + l31] = f2bf(oacc0[n][r]);
            op[(size_t)(qw + 32 + rr) * CDIM + h * HD + n * 32 + l31] = f2bf(oacc1[n][r]);
        }
}

// ---------------------------------------------------------------------------
// Combine split-KV partials: out = sum(O_s) / sum(l_s), bf16 (in place s0).
// ---------------------------------------------------------------------------
__global__ __launch_bounds__(256) void combine_splits(const ushort_t* __restrict__ opart,
                                                      const float* __restrict__ lpart,
                                                      ushort_t* __restrict__ out,
                                                      int nsplit) {
    const size_t i4 = ((size_t)blockIdx.x * 256 + threadIdx.x) << 2;
    const int row = (int)(i4 >> 9);
    const int h = (int)((i4 & 511) >> 6);
    float l = 0.0f;
    for (int s = 0; s < nsplit; ++s)
        l += lpart[(size_t)s * L_SEQ * NH + (size_t)row * NH + h];
    const float inv = 1.0f / l;

    float acc[4] = {};
    for (int s = 0; s < nsplit; ++s) {
        ushort_t a[4];
        *reinterpret_cast<uint2*>(a) =
            *reinterpret_cast<const uint2*>(opart + (size_t)s * L_SEQ * CDIM + i4);
#pragma unroll
        for (int j = 0; j < 4; ++j) acc[j] += bf2f(a[j]);
    }
    ushort_t r[4];
#pragma unroll
    for (int j = 0; j < 4; ++j) r[j] = f2bf(acc[j] * inv);
    *reinterpret_cast<uint2*>(out + i4) = *reinterpret_cast<const uint2*>(r);
}

// ---------------------------------------------------------------------------
extern "C" void kernel_launch(void* const* d_in, const int* in_sizes, int n_in,
                              void* d_out, int out_size, void* d_ws, size_t ws_size,
                              hipStream_t stream) {
    const float* x   = (const float*)d_in[0];
    const float* Wq  = (const float*)d_in[1];
    const float* Wk  = (const float*)d_in[2];
    const float* Wv  = (const float*)d_in[3];
    const float* qnw = (const float*)d_in[4];
    const float* knw = (const float*)d_in[5];
    const float* Wo  = (const float*)d_in[6];
    float* out = (float*)d_out;

    char* p = (char*)d_ws;
    ushort_t* opart = (ushort_t*)p;                        // NSPLIT x 4MB bf16
    ushort_t* xb    = opart;                               // phase-1 alias
    ushort_t* abuf  = opart;                               // phase-3 alias
    char* q = p + (size_t)NSPLIT * L_SEQ * CDIM * 2;
    ushort_t* qbuf = (ushort_t*)q;
    ushort_t* kbuf = qbuf + (size_t)L_SEQ * CDIM;
    ushort_t* vtb  = kbuf + (size_t)L_SEQ * NKV * HD;
    ushort_t* wqb  = vtb  + (size_t)L_SEQ * NKV * HD;
    ushort_t* wkb  = wqb  + (size_t)CDIM * CDIM;
    ushort_t* wvb  = wkb  + (size_t)NKV * HD * CDIM;
    ushort_t* wob  = wvb  + (size_t)NKV * HD * CDIM;
    float*    lpart = (float*)(wob + (size_t)CDIM * CDIM);           // 512 KB
    float2*   rope_tab = (float2*)(lpart + (size_t)NSPLIT * L_SEQ * NH); // 1 MB

    const dim3 blk(256);

    // f32 -> bf16 conversions (x + all weights) + RoPE sin/cos table
    cvt_bf16<<<dim3(3200), blk, 0, stream>>>(x, Wq, Wk, Wv, Wo,
                                             xb, wqb, wkb, wvb, wob, rope_tab);

    // Fused QKV projections + RMSNorm + RoPE (table-driven, 768 blocks)
    qkv_gemm<<<dim3(768), blk, 0, stream>>>(xb, wqb, wkb, wvb, qnw, knw,
                                            rope_tab, qbuf, kbuf, vtb);

    // Attention: split-KV x NSPLIT, QR=64 per wave, unnormalized partials
    attn_mfma<<<dim3(L_SEQ / 256, NH, NSPLIT), blk, 0, stream>>>(qbuf, kbuf, vtb, opart, lpart);

    // Combine partials -> bf16 attn out (in place over split 0)
    combine_splits<<<dim3((L_SEQ * CDIM) / (256 * 4)), blk, 0, stream>>>(opart, lpart, abuf, NSPLIT);

    // Output projection (64^2 tiles, f32 out)
    gemm_bf16_nt<false><<<dim3(8, 64), blk, 0, stream>>>(abuf, wob, out, L_SEQ, CDIM, CDIM);
}